// Round 4
// baseline (106.054 us; speedup 1.0000x reference)
//
#include <hip/hip_runtime.h>
#include <hip/hip_bf16.h>
#include <math.h>

// Problem constants
#define BS 8
#define NQ 4096
#define E  256
#define NH 8
#define NP 4
#define HD 32
#define GW 64
#define GH 64
#define T  (BS * NQ)     // 32768
#define NPAD 384
#define MSTR 96          // meta row: 64 offsets + 32 logits (bf16)
#define TB 64            // tokens per fused block

typedef __attribute__((ext_vector_type(8))) short bf16x8;
typedef __attribute__((ext_vector_type(4))) float f32x4;
typedef __attribute__((ext_vector_type(8))) unsigned short u16x8;

__device__ __forceinline__ float b2f(unsigned short u) {
    union { unsigned int i; float f; } x; x.i = ((unsigned int)u) << 16; return x.f;
}
__device__ __forceinline__ unsigned short f2b(float f) {
    __hip_bfloat16 h = __float2bfloat16(f);
    return *reinterpret_cast<unsigned short*>(&h);
}
__device__ __forceinline__ void gload16(const void* g, void* l) {
    __builtin_amdgcn_global_load_lds(
        (__attribute__((address_space(1))) void*)g,
        (__attribute__((address_space(3))) void*)l, 16, 0, 0);
}

// ---------------------------------------------------------------------------
// prep: Wcat (NPAD x 256 bf16), Wo (256x256 bf16), bcat (fp32 NPAD)
// ---------------------------------------------------------------------------
__global__ __launch_bounds__(256) void prep_weights(
    const float* __restrict__ vw, const float* __restrict__ vb,
    const float* __restrict__ ow, const float* __restrict__ ob,
    const float* __restrict__ aw, const float* __restrict__ ab,
    const float* __restrict__ outw,
    unsigned short* __restrict__ Wcat, unsigned short* __restrict__ Wo,
    float* __restrict__ bcat)
{
    int i = blockIdx.x * 256 + threadIdx.x;
    if (i < NPAD * E) {
        int n = i >> 8, k = i & 255;
        float w = 0.f;
        if      (n < 256) w = vw[n * E + k];
        else if (n < 320) w = ow[(n - 256) * E + k];
        else if (n < 352) w = aw[(n - 320) * E + k];
        Wcat[i] = f2b(w);
    } else {
        int j = i - NPAD * E;
        if (j < E * E) Wo[j] = f2b(outw[j]);
    }
    if (i < NPAD) {
        float bv = 0.f;
        if      (i < 256) bv = vb[i];
        else if (i < 320) bv = ob[i - 256];
        else if (i < 352) bv = ab[i - 320];
        bcat[i] = bv;
    }
}

// ---------------------------------------------------------------------------
// GEMM1 (projection): 64 rows x 384 cols per block -> query read exactly once.
// 4 waves; wave w covers cols [w*96, w*96+96) (6 frags) x 64 rows (4 frags).
// A: fp32 query -> bf16 regs -> LDS granules [chunk][row] (chunk<4, row<64).
// B: Wcat via global_load_lds, granules [chunk][row] (chunk<4, row<384).
// Epilogue scatter: col<256 -> Vt[((b*8+h)*4096+q)*32+ch]; 256..351 -> Mt.
// ---------------------------------------------------------------------------
__global__ __launch_bounds__(256) void gemm_proj(
    const float* __restrict__ Aq,
    const unsigned short* __restrict__ W,
    const float* __restrict__ bias,
    unsigned short* __restrict__ Vt,
    unsigned short* __restrict__ Mt)
{
    // A: 256 granules (4KB) at [0,2048) shorts; B: 1536 granules at [2048,...)
    __shared__ __align__(16) unsigned short lds[2048 + 12288];

    const int tid  = threadIdx.x;
    const int lane = tid & 63;
    const int wave = tid >> 6;
    const int bm = blockIdx.x * 64;
    const int cb = wave * 96;

    const int arow   = tid >> 2;      // 0..63
    const int achunk = tid & 3;       // 0..3
    const int lrow   = lane & 15;
    const int lchunk = lane >> 4;
    const int K = 256;

    f32x4 acc[4][6] = {};

    for (int k0 = 0; k0 < K; k0 += 32) {
        // B: 1536 granules, 6 per thread, wave-contiguous
#pragma unroll
        for (int p = 0; p < 6; ++p) {
            int g = p * 256 + wave * 64 + lane;
            int row = g % 384, chunk = g / 384;
            gload16(W + (size_t)row * K + k0 + chunk * 8,
                    &lds[2048 + (size_t)g * 8]);
        }
        // A: fp32 -> bf16 -> LDS
        const float* ap = Aq + (size_t)(bm + arow) * K + k0 + achunk * 8;
        float4 f0 = *(const float4*)(ap + 0);
        float4 f1 = *(const float4*)(ap + 4);
        u16x8 g0;
        g0[0]=f2b(f0.x); g0[1]=f2b(f0.y); g0[2]=f2b(f0.z); g0[3]=f2b(f0.w);
        g0[4]=f2b(f1.x); g0[5]=f2b(f1.y); g0[6]=f2b(f1.z); g0[7]=f2b(f1.w);
        *(u16x8*)&lds[(size_t)(achunk * 64 + arow) * 8] = g0;
        __syncthreads();

        bf16x8 af[4], bfr[6];
#pragma unroll
        for (int m = 0; m < 4; ++m)
            af[m] = *(const bf16x8*)&lds[(size_t)(lchunk * 64 + m * 16 + lrow) * 8];
#pragma unroll
        for (int n = 0; n < 6; ++n)
            bfr[n] = *(const bf16x8*)&lds[2048 + (size_t)(lchunk * 384 + cb + n * 16 + lrow) * 8];

#pragma unroll
        for (int m = 0; m < 4; ++m)
#pragma unroll
            for (int n = 0; n < 6; ++n)
                acc[m][n] = __builtin_amdgcn_mfma_f32_16x16x32_bf16(
                    af[m], bfr[n], acc[m][n], 0, 0, 0);
        __syncthreads();
    }

    const int orow0 = (lane >> 4) * 4;
    const int ocol  = lane & 15;
#pragma unroll
    for (int n = 0; n < 6; ++n) {
        int colg = cb + n * 16 + ocol;
        if (colg >= 352) continue;
        float bv = bias[colg];
#pragma unroll
        for (int m = 0; m < 4; ++m) {
#pragma unroll
            for (int r = 0; r < 4; ++r) {
                int rowg = bm + m * 16 + orow0 + r;
                unsigned short v = f2b(acc[m][n][r] + bv);
                if (colg < 256) {
                    int b = rowg >> 12, q = rowg & 4095;
                    int h = colg >> 5, ch = colg & 31;
                    Vt[((size_t)(((b << 3) + h) << 12) + q) * 32 + ch] = v;
                } else if (colg < 320) {
                    Mt[(size_t)rowg * MSTR + (colg - 256)] = v;
                } else {
                    Mt[(size_t)rowg * MSTR + 64 + (colg - 320)] = v;
                }
            }
        }
    }
}

// ---------------------------------------------------------------------------
// Fused sample + output projection. One block = 64 tokens, 256 threads.
// Phase 1: bilinear sampling -> S-tile in LDS, granule = h*256 + d0*64 + lt
//          (so panel ks=h is the GEMM A k-step, chunk=d0, row=lt).
// Phase 2: 8 K-steps: Wo panel (256 cols x 32 k) via global_load_lds,
//          4 waves each 64 rows x 64 cols, fp32 out + bias + 2*query.
// XCD swizzle: blocks with (bid&7)==x handle batch x -> 2MB image per L2.
// ---------------------------------------------------------------------------
__global__ __launch_bounds__(256) void fused_sample_out(
    const unsigned short* __restrict__ Vt,
    const unsigned short* __restrict__ Mt,
    const unsigned short* __restrict__ Wo,
    const float* __restrict__ bias,
    const float* __restrict__ resid,
    float* __restrict__ Out)
{
    // S: 2048 granules (32KB) at [0,16384) shorts; B: 1024 granules (16KB)
    __shared__ __align__(16) unsigned short smem[16384 + 8192];

    const int bid = blockIdx.x;
    const int nb  = ((bid & 7) << 6) + (bid >> 3);   // bijective, 512 = 8*64
    const int t0  = nb * TB;
    const int b   = t0 >> 12;
    const int tid = threadIdx.x;
    const int lane = tid & 63;
    const int wave = tid >> 6;

    // ---------------- Phase 1: sampling ----------------
#pragma unroll
    for (int it = 0; it < 8; ++it) {
        int item = it * 256 + tid;          // 0..2047
        int d0 = item >> 9;                 // 0..3
        int h  = (item >> 6) & 7;
        int lt = item & 63;
        int t  = t0 + lt;
        int q  = t & 4095;

        const float refx = (float)(q & 63) * (64.0f / 63.0f);
        const float refy = (float)(q >> 6) * (64.0f / 63.0f);

        const unsigned short* mrow = Mt + (size_t)t * MSTR;
        u16x8  offv = *(const u16x8*)&mrow[h * 8];
        ushort4 lg  = *(const ushort4*)&mrow[64 + h * 4];

        float l0 = b2f(lg.x), l1 = b2f(lg.y), l2 = b2f(lg.z), l3 = b2f(lg.w);
        float m = fmaxf(fmaxf(l0, l1), fmaxf(l2, l3));
        float e0 = __expf(l0 - m), e1 = __expf(l1 - m);
        float e2 = __expf(l2 - m), e3 = __expf(l3 - m);
        float inv = 1.0f / (e0 + e1 + e2 + e3);
        float at[4] = {e0 * inv, e1 * inv, e2 * inv, e3 * inv};

        const unsigned short* vbase =
            Vt + ((size_t)(((b << 3) + h) << 12)) * 32 + d0 * 8;

        float acc[8] = {};
#pragma unroll
        for (int p = 0; p < NP; ++p) {
            float ox = b2f(offv[2 * p]);
            float oy = b2f(offv[2 * p + 1]);
            float px = refx + ox - 0.5f;
            float py = refy + oy - 0.5f;
            float fx = floorf(px), fy = floorf(py);
            int x0 = (int)fx, y0 = (int)fy;
            float wx = px - fx, wy = py - fy;
            float a = at[p];

            float w00 = (1.f - wx) * (1.f - wy) * a;
            float w10 = wx * (1.f - wy) * a;
            float w01 = (1.f - wx) * wy * a;
            float w11 = wx * wy * a;

            int x1 = x0 + 1, y1 = y0 + 1;
            bool vx0 = (x0 >= 0) & (x0 < GW);
            bool vx1 = (x1 >= 0) & (x1 < GW);
            bool vy0 = (y0 >= 0) & (y0 < GH);
            bool vy1 = (y1 >= 0) & (y1 < GH);

#define CORNER(Y, X, WT)                                                      \
            {                                                                 \
                u16x8 g = *(const u16x8*)&vbase[(size_t)((Y) * GW + (X)) * 32];\
                _Pragma("unroll")                                             \
                for (int j = 0; j < 8; ++j) acc[j] += (WT) * b2f(g[j]);       \
            }
            if (vy0 & vx0) CORNER(y0, x0, w00);
            if (vy0 & vx1) CORNER(y0, x1, w10);
            if (vy1 & vx0) CORNER(y1, x0, w01);
            if (vy1 & vx1) CORNER(y1, x1, w11);
#undef CORNER
        }

        u16x8 o;
#pragma unroll
        for (int j = 0; j < 8; ++j) o[j] = f2b(acc[j]);
        *(u16x8*)&smem[(size_t)(h * 256 + d0 * 64 + lt) * 8] = o;
    }
    __syncthreads();

    // ---------------- Phase 2: output GEMM ----------------
    const int lrow   = lane & 15;
    const int lchunk = lane >> 4;
    const int cb = wave * 64;

    f32x4 acc[4][4] = {};

    for (int ks = 0; ks < 8; ++ks) {
        // stage Wo panel: cols 0..255 x k [ks*32, +32): 1024 granules
#pragma unroll
        for (int p = 0; p < 4; ++p) {
            int g = p * 256 + wave * 64 + lane;
            int row = g & 255, chunk = g >> 8;
            gload16(Wo + (size_t)row * 256 + ks * 32 + chunk * 8,
                    &smem[16384 + (size_t)g * 8]);
        }
        __syncthreads();

        bf16x8 af[4], bfr[4];
#pragma unroll
        for (int m = 0; m < 4; ++m)
            af[m] = *(const bf16x8*)&smem[(size_t)(ks * 256 + lchunk * 64 + m * 16 + lrow) * 8];
#pragma unroll
        for (int n = 0; n < 4; ++n)
            bfr[n] = *(const bf16x8*)&smem[16384 + (size_t)(lchunk * 256 + cb + n * 16 + lrow) * 8];

#pragma unroll
        for (int m = 0; m < 4; ++m)
#pragma unroll
            for (int n = 0; n < 4; ++n)
                acc[m][n] = __builtin_amdgcn_mfma_f32_16x16x32_bf16(
                    af[m], bfr[n], acc[m][n], 0, 0, 0);
        __syncthreads();
    }

    const int orow0 = (lane >> 4) * 4;
    const int ocol  = lane & 15;
#pragma unroll
    for (int m = 0; m < 4; ++m) {
#pragma unroll
        for (int n = 0; n < 4; ++n) {
            int colg = cb + n * 16 + ocol;
            float bv = bias[colg];
#pragma unroll
            for (int r = 0; r < 4; ++r) {
                int rowg = t0 + m * 16 + orow0 + r;
                Out[(size_t)rowg * 256 + colg] =
                    acc[m][n][r] + bv + 2.0f * resid[(size_t)rowg * 256 + colg];
            }
        }
    }
}

// ---------------------------------------------------------------------------
extern "C" void kernel_launch(void* const* d_in, const int* in_sizes, int n_in,
                              void* d_out, int out_size, void* d_ws, size_t ws_size,
                              hipStream_t stream)
{
    const float* query   = (const float*)d_in[0];
    const float* value_w = (const float*)d_in[1];
    const float* value_b = (const float*)d_in[2];
    const float* off_w   = (const float*)d_in[3];
    const float* off_b   = (const float*)d_in[4];
    const float* attn_w  = (const float*)d_in[5];
    const float* attn_b  = (const float*)d_in[6];
    const float* out_w   = (const float*)d_in[7];
    const float* out_b   = (const float*)d_in[8];

    char* w = (char*)d_ws;
    unsigned short* Vt   = (unsigned short*)w;  w += (size_t)T * E * 2;      // 16 MB
    unsigned short* Mt   = (unsigned short*)w;  w += (size_t)T * MSTR * 2;   // 6 MB
    unsigned short* Wcat = (unsigned short*)w;  w += (size_t)NPAD * E * 2;
    unsigned short* Wo   = (unsigned short*)w;  w += (size_t)E * E * 2;
    float*          bcat = (float*)w;

    prep_weights<<<(NPAD * E + E * E + 255) / 256, 256, 0, stream>>>(
        value_w, value_b, off_w, off_b, attn_w, attn_b, out_w, Wcat, Wo, bcat);

    gemm_proj<<<T / 64, 256, 0, stream>>>(query, Wcat, bcat, Vt, Mt);

    fused_sample_out<<<T / TB, 256, 0, stream>>>(
        Vt, Mt, Wo, out_b, query, (float*)d_out);
}